// Round 13
// baseline (314.757 us; speedup 1.0000x reference)
//
#include <hip/hip_runtime.h>
#include <hip/hip_cooperative_groups.h>
#include <math.h>

namespace cg = cooperative_groups;

#define B 4
#define DEC 256
#define ENC 256
#define HDIM 512

// exp2(x*TANH_SCALE) == e^{2x};  tanh(x) = 1 - 2/(1+e^{2x})
#define TANH_SCALE 2.8853900817779268f
#define LOG2E 1.4426950408889634f

__device__ __forceinline__ float fast_exp2(float x) { return __builtin_amdgcn_exp2f(x); }
__device__ __forceinline__ float fast_rcp(float x)  { return __builtin_amdgcn_rcpf(x); }

typedef __attribute__((ext_vector_type(8))) short bf16x8;
typedef __attribute__((ext_vector_type(4))) short bf16x4;
typedef __attribute__((ext_vector_type(4))) float f32x4;
typedef __attribute__((ext_vector_type(4))) unsigned int u32x4;

__device__ __forceinline__ unsigned short bf16_rne(float x) {
    unsigned u = __float_as_uint(x);
    return (unsigned short)((u + 0x7FFFu + ((u >> 16) & 1u)) >> 16);
}
__device__ __forceinline__ float bf16_to_f(unsigned short h) {
    return __uint_as_float((unsigned)h << 16);
}

// Blocked-transpose W layout (shorts): ofs(m,k) = (m/16)*8192 + (k/8)*128 + (m%16)*8 + k%8
#define W_OFS(m, k) ((((long)(m) >> 4) << 13) + (((long)(k) >> 3) << 7) + (((m) & 15) << 3) + ((k) & 7))

struct KArgs {
    const float* dec; const float* enc; const float* Wmlp; const float* bmlp; const float* wo;
    const unsigned char* extm;
    float* ctx; float* attn;
    unsigned short *Xh_e, *Xl_e, *Xh_d, *Xl_d, *Wh_e, *Wl_e, *Wh_d, *Wl_d;
    unsigned int* ET2; float* Dmat; unsigned char* padm;
};

// ---------------------------------------------------------------------------
// Single cooperative kernel: 512 blocks x 256 thr (2 blocks/CU co-resident).
// Phases (proven R12 bodies, re-indexed) separated by grid.sync():
//   1 convert  (2 units/block of the old 1024-block grid)
//   2 proj     (bid -> old (16,16,2))
//   3 attn     (bid -> old (128,4))
//   4 ctx      (512 blocks: 8 d-rows x 128-h stripes)
// LDS: one 8 KB arena reused by phases 3 (6.2 KB) and 4 (8 KB).
// ---------------------------------------------------------------------------
__global__ __launch_bounds__(256, 2) void fused_kernel(KArgs a)
{
    cg::grid_group gridg = cg::this_grid();
    __shared__ __align__(16) char smem[8192];
    const int tid = threadIdx.x;
    const int bid = blockIdx.x;

    // ---------------- phase 1: convert (+ pad mask) ----------------
    for (int u = bid; u < 1024; u += 512) {
        const int z = u >> 8, bx = u & 255;
        if (z < 2) {
            const float* X = z ? a.dec : a.enc;
            unsigned short* H = z ? a.Xh_d : a.Xh_e;
            unsigned short* L = z ? a.Xl_d : a.Xl_e;
            const long i8 = ((long)bx * 256 + tid) * 8;
            float4 v0 = *(const float4*)(X + i8);
            float4 v1 = *(const float4*)(X + i8 + 4);
            if (z == 0 && (i8 & 511) == 0)
                a.padm[i8 >> 9] = (v0.x == 0.0f) ? 1 : 0;
            float xs[8] = {v0.x, v0.y, v0.z, v0.w, v1.x, v1.y, v1.z, v1.w};
            bf16x8 hv, lv;
#pragma unroll
            for (int j = 0; j < 8; ++j) {
                unsigned short h = bf16_rne(xs[j]);
                hv[j] = (short)h;
                lv[j] = (short)bf16_rne(xs[j] - bf16_to_f(h));
            }
            *(bf16x8*)(H + i8) = hv;
            *(bf16x8*)(L + i8) = lv;
        } else {
            const float* Wsrc = a.Wmlp + (z == 3 ? (long)HDIM * HDIM : 0);
            unsigned short* H = (z == 3) ? a.Wh_d : a.Wh_e;
            unsigned short* L = (z == 3) ? a.Wl_d : a.Wl_e;
            const int t = bx * 256 + tid;
            const int m = t & 511;
            const int k0 = (t >> 9) << 2;
            bf16x4 hv, lv;
#pragma unroll
            for (int j = 0; j < 4; ++j) {
                float x = Wsrc[(long)(k0 + j) * 512 + m];
                unsigned short h = bf16_rne(x);
                hv[j] = (short)h;
                lv[j] = (short)bf16_rne(x - bf16_to_f(h));
            }
            const long ofs = W_OFS(m, k0);
            *(bf16x4*)(H + ofs) = hv;
            *(bf16x4*)(L + ofs) = lv;
        }
    }
    gridg.sync();

    // ---------------- phase 2: proj via MFMA ----------------
    {
        const int wave = tid >> 6, lane = tid & 63;
        const int z = bid >> 8;
        const int r0w = (bid & 15) * 64 + wave * 16;
        const int m0 = ((bid >> 4) & 15) * 32;
        const unsigned short* Xh = z ? a.Xh_d : a.Xh_e;
        const unsigned short* Xl = z ? a.Xl_d : a.Xl_e;
        const unsigned short* Wh = z ? a.Wh_d : a.Wh_e;
        const unsigned short* Wl = z ? a.Wl_d : a.Wl_e;

        const int col = lane & 15;
        const int quad = lane >> 4;

        const unsigned short* pah = Xh + (long)(r0w + col) * 512 + quad * 8;
        const unsigned short* pal = Xl + (long)(r0w + col) * 512 + quad * 8;
        const long bofs = ((long)(m0 >> 4) << 13) + (quad << 7) + (col << 3);
        const unsigned short* pb0h = Wh + bofs;
        const unsigned short* pb0l = Wl + bofs;
        const unsigned short* pb1h = Wh + bofs + 8192;
        const unsigned short* pb1l = Wl + bofs + 8192;

        f32x4 a0h = {0.f,0.f,0.f,0.f}, a0x = {0.f,0.f,0.f,0.f};
        f32x4 a1h = {0.f,0.f,0.f,0.f}, a1x = {0.f,0.f,0.f,0.f};

        bf16x8 Ah = *(const bf16x8*)pah,  Al = *(const bf16x8*)pal;
        bf16x8 B0h = *(const bf16x8*)pb0h, B0l = *(const bf16x8*)pb0l;
        bf16x8 B1h = *(const bf16x8*)pb1h, B1l = *(const bf16x8*)pb1l;

#pragma unroll 1
        for (int k0 = 0; k0 < 512; k0 += 32) {
            bf16x8 nAh = Ah, nAl = Al, nB0h = B0h, nB0l = B0l, nB1h = B1h, nB1l = B1l;
            if (k0 + 32 < 512) {
                nAh = *(const bf16x8*)(pah + k0 + 32);
                nAl = *(const bf16x8*)(pal + k0 + 32);
                const long ko = (long)(k0 + 32) << 4;
                nB0h = *(const bf16x8*)(pb0h + ko);
                nB0l = *(const bf16x8*)(pb0l + ko);
                nB1h = *(const bf16x8*)(pb1h + ko);
                nB1l = *(const bf16x8*)(pb1l + ko);
            }
            a0h = __builtin_amdgcn_mfma_f32_16x16x32_bf16(Ah, B0h, a0h, 0, 0, 0);
            a1h = __builtin_amdgcn_mfma_f32_16x16x32_bf16(Ah, B1h, a1h, 0, 0, 0);
            a0x = __builtin_amdgcn_mfma_f32_16x16x32_bf16(Ah, B0l, a0x, 0, 0, 0);
            a1x = __builtin_amdgcn_mfma_f32_16x16x32_bf16(Ah, B1l, a1x, 0, 0, 0);
            a0x = __builtin_amdgcn_mfma_f32_16x16x32_bf16(Al, B0h, a0x, 0, 0, 0);
            a1x = __builtin_amdgcn_mfma_f32_16x16x32_bf16(Al, B1h, a1x, 0, 0, 0);
            Ah = nAh; Al = nAl; B0h = nB0h; B0l = nB0l; B1h = nB1h; B1l = nB1l;
        }

        if (z == 0) {
            const int batch = r0w >> 8;
            const int e0 = (r0w & 255) + quad * 4;
            const int p = ((bid >> 4) & 15) * 16 + col;   // pair (m, m+16)
            u32x4 v;
#pragma unroll
            for (int i = 0; i < 4; ++i) {
                float E0 = fast_exp2((a0h[i] + a0x[i]) * TANH_SCALE);
                float E1 = fast_exp2((a1h[i] + a1x[i]) * TANH_SCALE);
                v[i] = ((unsigned)bf16_rne(E1) << 16) | (unsigned)bf16_rne(E0);
            }
            *(u32x4*)&a.ET2[(long)batch * 65536 + (long)p * 256 + e0] = v;
        } else {
            const float bq0 = a.bmlp[m0 + col];
            const float bq1 = a.bmlp[m0 + 16 + col];
            const int r = r0w + quad * 4;
#pragma unroll
            for (int i = 0; i < 4; ++i) {
                a.Dmat[(long)(r + i) * HDIM + m0 + col] =
                    fast_exp2((a0h[i] + a0x[i] + bq0) * TANH_SCALE);
                a.Dmat[(long)(r + i) * HDIM + m0 + 16 + col] =
                    fast_exp2((a1h[i] + a1x[i] + bq1) * TANH_SCALE);
            }
        }
    }
    gridg.sync();

    // ---------------- phase 3: attn (logits + masks + softmax) ----------------
    {
        float* d0s = (float*)smem;
        float* d1s = d0s + 512;
        float* wos = d1s + 512;
        float (*red)[4][2] = (float(*)[4][2])(wos + 512);

        const int lane = tid & 63, wave = tid >> 6;
        const int b = bid >> 7, d0 = (bid & 127) * 2;

        const float* D0 = a.Dmat + ((long)b * DEC + d0) * HDIM;
        const unsigned int* ecol = a.ET2 + (long)b * 65536 + tid;

        *(float2*)&d0s[tid * 2] = *(const float2*)&D0[tid * 2];
        *(float2*)&d1s[tid * 2] = *(const float2*)&D0[HDIM + tid * 2];
        *(float2*)&wos[tid * 2] = *(const float2*)&a.wo[tid * 2];

        unsigned int ev[8], nv[8];
#pragma unroll
        for (int j = 0; j < 8; ++j) ev[j] = ecol[j * 256];
        __syncthreads();

        float acc0 = 0.f, acc1 = 0.f;
        for (int c = 0; c < 256; c += 8) {               // 8 pairs = 16 m per chunk
            if (c + 8 < 256) {
#pragma unroll
                for (int j = 0; j < 8; ++j) nv[j] = ecol[(c + 8 + j) * 256];
            }
            const int mlb = ((c >> 4) << 5) + (c & 15);  // m_lo base
            const int mhb = mlb + 16;
            float4 dv0l[2], dv0h[2], dv1l[2], dv1h[2], wvl[2], wvh[2];
#pragma unroll
            for (int q = 0; q < 2; ++q) {
                dv0l[q] = *(const float4*)&d0s[mlb + q * 4];
                dv0h[q] = *(const float4*)&d0s[mhb + q * 4];
                dv1l[q] = *(const float4*)&d1s[mlb + q * 4];
                dv1h[q] = *(const float4*)&d1s[mhb + q * 4];
                wvl[q]  = *(const float4*)&wos[mlb + q * 4];
                wvh[q]  = *(const float4*)&wos[mhb + q * 4];
            }
#pragma unroll
            for (int j = 0; j < 8; ++j) {
                const float elo = __uint_as_float(ev[j] << 16);
                const float ehi = __uint_as_float(ev[j] & 0xFFFF0000u);
                const float wl = ((const float*)&wvl[j >> 2])[j & 3];
                const float wh = ((const float*)&wvh[j >> 2])[j & 3];
                float t;
                t = fmaf(elo, ((const float*)&dv0l[j >> 2])[j & 3], 1.0f);
                acc0 = fmaf(wl, fast_rcp(t), acc0);
                t = fmaf(ehi, ((const float*)&dv0h[j >> 2])[j & 3], 1.0f);
                acc0 = fmaf(wh, fast_rcp(t), acc0);
                t = fmaf(elo, ((const float*)&dv1l[j >> 2])[j & 3], 1.0f);
                acc1 = fmaf(wl, fast_rcp(t), acc1);
                t = fmaf(ehi, ((const float*)&dv1h[j >> 2])[j & 3], 1.0f);
                acc1 = fmaf(wh, fast_rcp(t), acc1);
            }
#pragma unroll
            for (int j = 0; j < 8; ++j) ev[j] = nv[j];
        }

        const int e = tid;
        const bool pad = (a.padm[b * ENC + e] != 0);
        const bool x0m = a.extm[((long)(b * DEC) + d0) * ENC + e] != 0;
        const bool x1m = a.extm[((long)(b * DEC) + d0 + 1) * ENC + e] != 0;
        float l0 = (pad || x0m) ? -__builtin_inff() : -2.0f * acc0;
        float l1 = (pad || x1m) ? -__builtin_inff() : -2.0f * acc1;

        float m0 = l0, m1 = l1;
#pragma unroll
        for (int off = 32; off >= 1; off >>= 1) {
            m0 = fmaxf(m0, __shfl_xor(m0, off, 64));
            m1 = fmaxf(m1, __shfl_xor(m1, off, 64));
        }
        if (lane == 0) { red[0][wave][0] = m0; red[0][wave][1] = m1; }
        __syncthreads();
        const float gm0 = fmaxf(fmaxf(red[0][0][0], red[0][1][0]), fmaxf(red[0][2][0], red[0][3][0]));
        const float gm1 = fmaxf(fmaxf(red[0][0][1], red[0][1][1]), fmaxf(red[0][2][1], red[0][3][1]));
        float p0 = fast_exp2((l0 - gm0) * LOG2E);
        float p1 = fast_exp2((l1 - gm1) * LOG2E);
        float s0 = p0, s1 = p1;
#pragma unroll
        for (int off = 32; off >= 1; off >>= 1) {
            s0 += __shfl_xor(s0, off, 64);
            s1 += __shfl_xor(s1, off, 64);
        }
        if (lane == 0) { red[1][wave][0] = s0; red[1][wave][1] = s1; }
        __syncthreads();
        const float gs0 = red[1][0][0] + red[1][1][0] + red[1][2][0] + red[1][3][0];
        const float gs1 = red[1][0][1] + red[1][1][1] + red[1][2][1] + red[1][3][1];
        a.attn[((long)(b * DEC) + d0) * ENC + e] = p0 * fast_rcp(gs0);
        a.attn[((long)(b * DEC) + d0 + 1) * ENC + e] = p1 * fast_rcp(gs1);
    }
    gridg.sync();

    // ---------------- phase 4: ctx = attn @ enc (8 rows x 128-h stripe) ----------------
    {
        float* as8 = (float*)smem;                   // [8][256]
        const int rg = bid & 127, hs = bid >> 7;
        const int r0 = rg * 8;                       // global row (b*DEC + d)
        const int bb = r0 >> 8;
        const int tx = tid & 31, ty = tid >> 5;      // h-quad, local row
        const int h0 = hs * 128 + tx * 4;
        const float* We = a.enc + (long)bb * ENC * HDIM + h0;
        const float* ag = a.attn + (long)r0 * ENC;

        *(float4*)&as8[tid * 4] = *(const float4*)&ag[tid * 4];
        *(float4*)&as8[(tid + 256) * 4] = *(const float4*)&ag[(tid + 256) * 4];

        float4 Wa[8], Wb[8];
#pragma unroll
        for (int kk = 0; kk < 8; ++kk) Wa[kk] = *(const float4*)&We[(long)kk * HDIM];
        __syncthreads();

        float ac0 = 0.f, ac1 = 0.f, ac2 = 0.f, ac3 = 0.f;
        for (int e0 = 0; e0 < 256; e0 += 16) {
#pragma unroll
            for (int kk = 0; kk < 8; ++kk)
                Wb[kk] = *(const float4*)&We[(long)(e0 + 8 + kk) * HDIM];
#pragma unroll
            for (int kk = 0; kk < 8; ++kk) {
                float av = as8[ty * 256 + e0 + kk];
                float4 w = Wa[kk];
                ac0 = fmaf(av, w.x, ac0);
                ac1 = fmaf(av, w.y, ac1);
                ac2 = fmaf(av, w.z, ac2);
                ac3 = fmaf(av, w.w, ac3);
            }
            if (e0 + 16 < 256) {
#pragma unroll
                for (int kk = 0; kk < 8; ++kk)
                    Wa[kk] = *(const float4*)&We[(long)(e0 + 16 + kk) * HDIM];
            }
#pragma unroll
            for (int kk = 0; kk < 8; ++kk) {
                float av = as8[ty * 256 + e0 + 8 + kk];
                float4 w = Wb[kk];
                ac0 = fmaf(av, w.x, ac0);
                ac1 = fmaf(av, w.y, ac1);
                ac2 = fmaf(av, w.z, ac2);
                ac3 = fmaf(av, w.w, ac3);
            }
        }
        *(float4*)&a.ctx[(long)(r0 + ty) * HDIM + h0] = make_float4(ac0, ac1, ac2, ac3);
    }
}

// ---------------------------------------------------------------------------
extern "C" void kernel_launch(void* const* d_in, const int* in_sizes, int n_in,
                              void* d_out, int out_size, void* d_ws, size_t ws_size,
                              hipStream_t stream) {
    KArgs ha;
    ha.dec  = (const float*)d_in[0];
    ha.enc  = (const float*)d_in[1];
    ha.extm = (const unsigned char*)d_in[2];
    ha.Wmlp = (const float*)d_in[3];
    ha.bmlp = (const float*)d_in[4];
    ha.wo   = (const float*)d_in[5];
    // d_in[6] = b_out: additive constant, cancels in softmax

    ha.ctx  = (float*)d_out;                         // [B, DEC, H]
    ha.attn = ha.ctx + (size_t)B * DEC * HDIM;       // [B, DEC, ENC]

    const size_t F = (size_t)B * DEC * HDIM;         // 524288
    ha.ET2  = (unsigned int*)d_ws;                   // [B][256 pairs][256 e]
    ha.Dmat = (float*)(ha.ET2 + (size_t)B * 65536);  // [B*DEC][H]
    ha.Xh_e = (unsigned short*)(ha.Dmat + F);
    ha.Xl_e = ha.Xh_e + F;
    ha.Xh_d = ha.Xl_e + F;
    ha.Xl_d = ha.Xh_d + F;
    ha.Wh_e = ha.Xl_d + F;                           // blocked-T, 512*512
    ha.Wl_e = ha.Wh_e + HDIM * HDIM;
    ha.Wh_d = ha.Wl_e + HDIM * HDIM;
    ha.Wl_d = ha.Wh_d + HDIM * HDIM;
    ha.padm = (unsigned char*)(ha.Wl_d + HDIM * HDIM);   // [B*ENC]

    void* params[] = { (void*)&ha };
    hipLaunchCooperativeKernel((void*)fused_kernel, dim3(512), dim3(256),
                               params, 0, stream);
}

// Round 14
// 118.956 us; speedup vs baseline: 2.6460x; 2.6460x over previous
//
#include <hip/hip_runtime.h>
#include <math.h>

#define B 4
#define DEC 256
#define ENC 256
#define HDIM 512

// exp2(x*TANH_SCALE) == e^{2x};  tanh(x) = 1 - 2/(1+e^{2x})
#define TANH_SCALE 2.8853900817779268f
#define LOG2E 1.4426950408889634f

__device__ __forceinline__ float fast_exp2(float x) { return __builtin_amdgcn_exp2f(x); }
__device__ __forceinline__ float fast_rcp(float x)  { return __builtin_amdgcn_rcpf(x); }

typedef __attribute__((ext_vector_type(8))) short bf16x8;   // 8 bf16 = 4 VGPR
typedef __attribute__((ext_vector_type(4))) short bf16x4;
typedef __attribute__((ext_vector_type(4))) float f32x4;

__device__ __forceinline__ unsigned short bf16_rne(float x) {
    unsigned u = __float_as_uint(x);
    return (unsigned short)((u + 0x7FFFu + ((u >> 16) & 1u)) >> 16);
}
__device__ __forceinline__ float bf16_to_f(unsigned short h) {
    return __uint_as_float((unsigned)h << 16);
}

// Blocked-transpose W layout (shorts): ofs(m,k) = (m/16)*8192 + (k/8)*128 + (m%16)*8 + k%8
#define W_OFS(m, k) ((((long)(m) >> 4) << 13) + (((long)(k) >> 3) << 7) + (((m) & 15) << 3) + ((k) & 7))

// ---------------------------------------------------------------------------
// convert (R10-proven): fp32 -> bf16 hi/lo split.
//  z=0/1: X (enc/dec) -> Xh/Xl row-major. 8 els/thread.
//  z=2/3: W half -> blocked-transpose layout (128B-segment writes).
// ---------------------------------------------------------------------------
__global__ __launch_bounds__(256) void convert_kernel(
    const float* __restrict__ enc, const float* __restrict__ dec,
    const float* __restrict__ Wmlp,
    unsigned short* __restrict__ Xh_e, unsigned short* __restrict__ Xl_e,
    unsigned short* __restrict__ Xh_d, unsigned short* __restrict__ Xl_d,
    unsigned short* __restrict__ Wh_e, unsigned short* __restrict__ Wl_e,
    unsigned short* __restrict__ Wh_d, unsigned short* __restrict__ Wl_d)
{
    const int tid = threadIdx.x, z = blockIdx.z;
    if (z < 2) {
        const float* X = z ? dec : enc;
        unsigned short* H = z ? Xh_d : Xh_e;
        unsigned short* L = z ? Xl_d : Xl_e;
        const long i8 = ((long)blockIdx.x * 256 + tid) * 8;
        float4 v0 = *(const float4*)(X + i8);
        float4 v1 = *(const float4*)(X + i8 + 4);
        float xs[8] = {v0.x, v0.y, v0.z, v0.w, v1.x, v1.y, v1.z, v1.w};
        bf16x8 hv, lv;
#pragma unroll
        for (int j = 0; j < 8; ++j) {
            unsigned short h = bf16_rne(xs[j]);
            hv[j] = (short)h;
            lv[j] = (short)bf16_rne(xs[j] - bf16_to_f(h));
        }
        *(bf16x8*)(H + i8) = hv;
        *(bf16x8*)(L + i8) = lv;
    } else {
        const float* Wsrc = Wmlp + (z == 3 ? (long)HDIM * HDIM : 0);
        unsigned short* H = (z == 3) ? Wh_d : Wh_e;
        unsigned short* L = (z == 3) ? Wl_d : Wl_e;
        const int t = blockIdx.x * 256 + tid;
        const int m = t & 511;
        const int k0 = (t >> 9) << 2;
        bf16x4 hv, lv;
#pragma unroll
        for (int j = 0; j < 4; ++j) {
            float x = Wsrc[(long)(k0 + j) * 512 + m];
            unsigned short h = bf16_rne(x);
            hv[j] = (short)h;
            lv[j] = (short)bf16_rne(x - bf16_to_f(h));
        }
        const long ofs = W_OFS(m, k0);
        *(bf16x4*)(H + ofs) = hv;
        *(bf16x4*)(L + ofs) = lv;
    }
}

// ---------------------------------------------------------------------------
// proj via MFMA (R10-proven): wave = 16r x 32m (2 C-tiles), runtime K-loop
// with depth-1 ping-pong (bounded loads in flight), 4 acc chains, hi/lo
// 3-mfma scheme. grid (16, 16, 2) = 512 blocks.
// ---------------------------------------------------------------------------
__global__ __launch_bounds__(256) void proj_mfma_kernel(
    const unsigned short* __restrict__ Xh_e, const unsigned short* __restrict__ Xl_e,
    const unsigned short* __restrict__ Xh_d, const unsigned short* __restrict__ Xl_d,
    const unsigned short* __restrict__ Wh_e, const unsigned short* __restrict__ Wl_e,
    const unsigned short* __restrict__ Wh_d, const unsigned short* __restrict__ Wl_d,
    const float* __restrict__ bmlp,
    float* __restrict__ ET, float* __restrict__ Dmat)
{
    const int tid = threadIdx.x;
    const int wave = tid >> 6, lane = tid & 63;
    const int z = blockIdx.z;
    const int r0w = blockIdx.x * 64 + wave * 16;
    const int m0 = blockIdx.y * 32;
    const unsigned short* Xh = z ? Xh_d : Xh_e;
    const unsigned short* Xl = z ? Xl_d : Xl_e;
    const unsigned short* Wh = z ? Wh_d : Wh_e;
    const unsigned short* Wl = z ? Wl_d : Wl_e;

    const int col = lane & 15;
    const int quad = lane >> 4;

    const unsigned short* pah = Xh + (long)(r0w + col) * 512 + quad * 8;
    const unsigned short* pal = Xl + (long)(r0w + col) * 512 + quad * 8;
    const long bofs = ((long)(m0 >> 4) << 13) + (quad << 7) + (col << 3);
    const unsigned short* pb0h = Wh + bofs;
    const unsigned short* pb0l = Wl + bofs;
    const unsigned short* pb1h = Wh + bofs + 8192;
    const unsigned short* pb1l = Wl + bofs + 8192;

    f32x4 a0h = {0.f,0.f,0.f,0.f}, a0x = {0.f,0.f,0.f,0.f};
    f32x4 a1h = {0.f,0.f,0.f,0.f}, a1x = {0.f,0.f,0.f,0.f};

    bf16x8 Ah = *(const bf16x8*)pah,  Al = *(const bf16x8*)pal;
    bf16x8 B0h = *(const bf16x8*)pb0h, B0l = *(const bf16x8*)pb0l;
    bf16x8 B1h = *(const bf16x8*)pb1h, B1l = *(const bf16x8*)pb1l;

#pragma unroll 1
    for (int k0 = 0; k0 < 512; k0 += 32) {
        bf16x8 nAh = Ah, nAl = Al, nB0h = B0h, nB0l = B0l, nB1h = B1h, nB1l = B1l;
        if (k0 + 32 < 512) {
            nAh = *(const bf16x8*)(pah + k0 + 32);
            nAl = *(const bf16x8*)(pal + k0 + 32);
            const long ko = (long)(k0 + 32) << 4;
            nB0h = *(const bf16x8*)(pb0h + ko);
            nB0l = *(const bf16x8*)(pb0l + ko);
            nB1h = *(const bf16x8*)(pb1h + ko);
            nB1l = *(const bf16x8*)(pb1l + ko);
        }
        a0h = __builtin_amdgcn_mfma_f32_16x16x32_bf16(Ah, B0h, a0h, 0, 0, 0);
        a1h = __builtin_amdgcn_mfma_f32_16x16x32_bf16(Ah, B1h, a1h, 0, 0, 0);
        a0x = __builtin_amdgcn_mfma_f32_16x16x32_bf16(Ah, B0l, a0x, 0, 0, 0);
        a1x = __builtin_amdgcn_mfma_f32_16x16x32_bf16(Ah, B1l, a1x, 0, 0, 0);
        a0x = __builtin_amdgcn_mfma_f32_16x16x32_bf16(Al, B0h, a0x, 0, 0, 0);
        a1x = __builtin_amdgcn_mfma_f32_16x16x32_bf16(Al, B1h, a1x, 0, 0, 0);
        Ah = nAh; Al = nAl; B0h = nB0h; B0l = nB0l; B1h = nB1h; B1l = nB1l;
    }

    if (z == 0) {
        const int batch = r0w >> 8;
        const int e0 = (r0w & 255) + quad * 4;
        float* base = ET + (long)batch * HDIM * ENC;
        float4 v;
        v.x = fast_exp2((a0h[0] + a0x[0]) * TANH_SCALE);
        v.y = fast_exp2((a0h[1] + a0x[1]) * TANH_SCALE);
        v.z = fast_exp2((a0h[2] + a0x[2]) * TANH_SCALE);
        v.w = fast_exp2((a0h[3] + a0x[3]) * TANH_SCALE);
        *(float4*)&base[(long)(m0 + col) * ENC + e0] = v;
        v.x = fast_exp2((a1h[0] + a1x[0]) * TANH_SCALE);
        v.y = fast_exp2((a1h[1] + a1x[1]) * TANH_SCALE);
        v.z = fast_exp2((a1h[2] + a1x[2]) * TANH_SCALE);
        v.w = fast_exp2((a1h[3] + a1x[3]) * TANH_SCALE);
        *(float4*)&base[(long)(m0 + 16 + col) * ENC + e0] = v;
    } else {
        const float bq0 = bmlp[m0 + col];
        const float bq1 = bmlp[m0 + 16 + col];
        const int r = r0w + quad * 4;
#pragma unroll
        for (int i = 0; i < 4; ++i) {
            Dmat[(long)(r + i) * HDIM + m0 + col] =
                fast_exp2((a0h[i] + a0x[i] + bq0) * TANH_SCALE);
            Dmat[(long)(r + i) * HDIM + m0 + 16 + col] =
                fast_exp2((a1h[i] + a1x[i] + bq1) * TANH_SCALE);
        }
    }
}

// ---------------------------------------------------------------------------
// attn_partial (R10-proven): grid (64, 4, B) = 1024 blocks.
// Block: 4 d-rows x 256 e (thread=e) x 128 m (m-quarter).
// part[q][(b*DEC+d)*ENC+e] = sum_{m in quarter} wo[m]*rcp(fma(E,D,1))
// ---------------------------------------------------------------------------
__global__ __launch_bounds__(256) void attn_partial_kernel(
    const float* __restrict__ Dmat, const float* __restrict__ ET,
    const float* __restrict__ wo, float* __restrict__ part)
{
    __shared__ __align__(16) float ds[4][128];
    __shared__ __align__(16) float wos[128];

    const int tid = threadIdx.x;
    const int b = blockIdx.z, d0 = blockIdx.x * 4, mq = blockIdx.y;
    const int m0q = mq * 128;

    const float* Drow = Dmat + ((long)b * DEC + d0) * HDIM + m0q;
    if (tid < 128) {
#pragma unroll
        for (int r = 0; r < 4; ++r)
            ds[r][tid] = Drow[(long)r * HDIM + tid];
        wos[tid] = wo[m0q + tid];
    }

    const float* ecol = ET + (long)b * HDIM * ENC + (long)m0q * ENC + tid;

    float ev[16], nv[16];
#pragma unroll
    for (int j = 0; j < 16; ++j) ev[j] = ecol[j * ENC];
    __syncthreads();

    float acc[4] = {0.f, 0.f, 0.f, 0.f};
    for (int m = 0; m < 128; m += 16) {
        if (m + 16 < 128) {
#pragma unroll
            for (int j = 0; j < 16; ++j) nv[j] = ecol[(m + 16 + j) * ENC];
        }
        float4 dv[4][4], wv[4];
#pragma unroll
        for (int q = 0; q < 4; ++q) {
#pragma unroll
            for (int r = 0; r < 4; ++r)
                dv[r][q] = *(const float4*)&ds[r][m + q * 4];
            wv[q] = *(const float4*)&wos[m + q * 4];
        }
#pragma unroll
        for (int j = 0; j < 16; ++j) {
            float w = ((const float*)&wv[j >> 2])[j & 3];
#pragma unroll
            for (int r = 0; r < 4; ++r) {
                float t = fmaf(ev[j], ((const float*)&dv[r][j >> 2])[j & 3], 1.0f);
                acc[r] = fmaf(w, fast_rcp(t), acc[r]);
            }
        }
#pragma unroll
        for (int j = 0; j < 16; ++j) ev[j] = nv[j];
    }

    float* pq = part + (long)mq * (B * DEC * ENC);
#pragma unroll
    for (int r = 0; r < 4; ++r)
        pq[((long)b * DEC + d0 + r) * ENC + tid] = acc[r];
}

// ---------------------------------------------------------------------------
// attn_finish (R10-proven): sum 4 partials, masks, softmax, write.
// ---------------------------------------------------------------------------
__global__ __launch_bounds__(256) void attn_finish_kernel(
    const float* __restrict__ part,
    const float* __restrict__ enc, const unsigned char* __restrict__ extm,
    float* __restrict__ attn_out)
{
    __shared__ float red[2][4][2];
    const int tid = threadIdx.x, lane = tid & 63, wave = tid >> 6;
    const int b = blockIdx.y, d0 = blockIdx.x * 2;
    const long g0 = (long)b * DEC + d0;
    const long NQ = (long)B * DEC * ENC;

    float a0 = 0.f, a1 = 0.f;
#pragma unroll
    for (int q = 0; q < 4; ++q) {
        a0 += part[q * NQ + g0 * ENC + tid];
        a1 += part[q * NQ + (g0 + 1) * ENC + tid];
    }

    const int e = tid;
    const bool pad = (enc[((long)b * ENC + e) * HDIM] == 0.0f);
    const bool x0m = extm[g0 * ENC + e] != 0;
    const bool x1m = extm[(g0 + 1) * ENC + e] != 0;
    float l0 = (pad || x0m) ? -__builtin_inff() : -2.0f * a0;
    float l1 = (pad || x1m) ? -__builtin_inff() : -2.0f * a1;

    float m0 = l0, m1 = l1;
#pragma unroll
    for (int off = 32; off >= 1; off >>= 1) {
        m0 = fmaxf(m0, __shfl_xor(m0, off, 64));
        m1 = fmaxf(m1, __shfl_xor(m1, off, 64));
    }
    if (lane == 0) { red[0][wave][0] = m0; red[0][wave][1] = m1; }
    __syncthreads();
    const float gm0 = fmaxf(fmaxf(red[0][0][0], red[0][1][0]), fmaxf(red[0][2][0], red[0][3][0]));
    const float gm1 = fmaxf(fmaxf(red[0][0][1], red[0][1][1]), fmaxf(red[0][2][1], red[0][3][1]));
    float p0 = fast_exp2((l0 - gm0) * LOG2E);
    float p1 = fast_exp2((l1 - gm1) * LOG2E);
    float s0 = p0, s1 = p1;
#pragma unroll
    for (int off = 32; off >= 1; off >>= 1) {
        s0 += __shfl_xor(s0, off, 64);
        s1 += __shfl_xor(s1, off, 64);
    }
    if (lane == 0) { red[1][wave][0] = s0; red[1][wave][1] = s1; }
    __syncthreads();
    const float gs0 = red[1][0][0] + red[1][1][0] + red[1][2][0] + red[1][3][0];
    const float gs1 = red[1][0][1] + red[1][1][1] + red[1][2][1] + red[1][3][1];
    attn_out[g0 * ENC + e] = p0 * fast_rcp(gs0);
    attn_out[(g0 + 1) * ENC + e] = p1 * fast_rcp(gs1);
}

// ---------------------------------------------------------------------------
// ctx v3 (R10-proven): 8 d-rows x 256-h stripe per block.
// ---------------------------------------------------------------------------
#define C5_LOADW(WB, KOFF)                                                  \
    _Pragma("unroll")                                                       \
    for (int kk = 0; kk < 8; ++kk)                                          \
        WB[kk] = *(const float4*)&We[(long)((KOFF) + kk) * HDIM];

#define C5_FMA(WB, KOFF)                                                    \
    _Pragma("unroll")                                                       \
    for (int q = 0; q < 2; ++q) {                                           \
        float4 xq0 = *(const float4*)&as8[r0l][(KOFF) + q * 4];             \
        float4 xq1 = *(const float4*)&as8[r0l + 1][(KOFF) + q * 4];         \
        _Pragma("unroll")                                                   \
        for (int kk = 0; kk < 4; ++kk) {                                    \
            float4 w = WB[q * 4 + kk];                                      \
            float xv0 = ((const float*)&xq0)[kk];                           \
            float xv1 = ((const float*)&xq1)[kk];                           \
            acc[0][0] = fmaf(xv0, w.x, acc[0][0]);                          \
            acc[0][1] = fmaf(xv0, w.y, acc[0][1]);                          \
            acc[0][2] = fmaf(xv0, w.z, acc[0][2]);                          \
            acc[0][3] = fmaf(xv0, w.w, acc[0][3]);                          \
            acc[1][0] = fmaf(xv1, w.x, acc[1][0]);                          \
            acc[1][1] = fmaf(xv1, w.y, acc[1][1]);                          \
            acc[1][2] = fmaf(xv1, w.z, acc[1][2]);                          \
            acc[1][3] = fmaf(xv1, w.w, acc[1][3]);                          \
        }                                                                   \
    }

__global__ __launch_bounds__(256) void context_kernel(
    const float* __restrict__ attn, const float* __restrict__ enc,
    float* __restrict__ ctx)
{
    __shared__ __align__(16) float as8[8][ENC];
    const int tid = threadIdx.x;
    const int tx = tid & 63, ty = tid >> 6;
    const int r0 = blockIdx.x * 8;
    const int b = r0 >> 8;
    const int h0 = blockIdx.y * 256 + tx * 4;
    const int r0l = ty * 2;
    const float* We = enc + (long)b * ENC * HDIM + h0;

    {
        const float* ag = attn + (long)r0 * ENC;
#pragma unroll
        for (int i = 0; i < 2; ++i) {
            int idx = (tid + i * 256) * 4;
            *(float4*)&as8[0][idx] = *(const float4*)&ag[idx];
        }
    }

    float acc[2][4] = {};
    float4 Wa[8], Wb[8];
    C5_LOADW(Wa, 0)
    __syncthreads();

    for (int k0 = 0; k0 < ENC; k0 += 16) {
        C5_LOADW(Wb, k0 + 8)
        C5_FMA(Wa, k0)
        if (k0 + 16 < ENC) { C5_LOADW(Wa, k0 + 16) }
        C5_FMA(Wb, k0 + 8)
    }

#pragma unroll
    for (int i = 0; i < 2; ++i)
        *(float4*)&ctx[(long)(r0 + r0l + i) * HDIM + h0] =
            make_float4(acc[i][0], acc[i][1], acc[i][2], acc[i][3]);
}

// ---------------------------------------------------------------------------
extern "C" void kernel_launch(void* const* d_in, const int* in_sizes, int n_in,
                              void* d_out, int out_size, void* d_ws, size_t ws_size,
                              hipStream_t stream) {
    const float* dec = (const float*)d_in[0];
    const float* enc = (const float*)d_in[1];
    const unsigned char* extm = (const unsigned char*)d_in[2];
    const float* Wmlp = (const float*)d_in[3];
    const float* bmlp = (const float*)d_in[4];
    const float* Wout = (const float*)d_in[5];
    // d_in[6] = b_out: additive constant, cancels in softmax

    float* ctx = (float*)d_out;                    // [B, DEC, H]
    float* attn = ctx + (size_t)B * DEC * HDIM;    // [B, DEC, ENC]

    const size_t F = (size_t)B * DEC * HDIM;       // 524288
    float* ET = (float*)d_ws;                      // [B][H][ENC] fp32
    float* Dmat = ET + F;                          // [B*DEC][H] fp32
    unsigned short* Xh_e = (unsigned short*)(Dmat + F);
    unsigned short* Xl_e = Xh_e + F;
    unsigned short* Xh_d = Xl_e + F;
    unsigned short* Xl_d = Xh_d + F;
    unsigned short* Wh_e = Xl_d + F;               // blocked-T layout, 512*512
    unsigned short* Wl_e = Wh_e + HDIM * HDIM;
    unsigned short* Wh_d = Wl_e + HDIM * HDIM;
    unsigned short* Wl_d = Wh_d + HDIM * HDIM;
    float* part = (float*)(Wl_d + HDIM * HDIM);    // [4][B*DEC][ENC] fp32

    convert_kernel<<<dim3(256, 1, 4), 256, 0, stream>>>(
        enc, dec, Wmlp, Xh_e, Xl_e, Xh_d, Xl_d, Wh_e, Wl_e, Wh_d, Wl_d);
    proj_mfma_kernel<<<dim3(16, 16, 2), 256, 0, stream>>>(
        Xh_e, Xl_e, Xh_d, Xl_d, Wh_e, Wl_e, Wh_d, Wl_d, bmlp, ET, Dmat);
    attn_partial_kernel<<<dim3(DEC / 4, 4, B), 256, 0, stream>>>(Dmat, ET, Wout, part);
    attn_finish_kernel<<<dim3(DEC / 2, B), 256, 0, stream>>>(part, enc, extm, attn);
    context_kernel<<<dim3(128, 2), 256, 0, stream>>>(attn, enc, ctx);
}